// Round 1
// baseline (1268.486 us; speedup 1.0000x reference)
//
#include <hip/hip_runtime.h>
#include <math.h>

#define B_ 4
#define S_ 1024
#define D_ 1024
#define H_ 16
#define DK_ 64

// ---------------------------------------------------------------------------
// Tiled fp32 GEMM: C[M,N] = X[M,K] @ W[K,N] + bias (+ resid). 64x64 tile,
// BK=16, 256 threads, 4x4 per thread. HEADED=1 writes [B,H,S,DK] layout.
// ---------------------------------------------------------------------------
template<int HEADED>
__global__ __launch_bounds__(256) void gemm64(
    const float* __restrict__ X, const float* __restrict__ W,
    const float* __restrict__ bias, const float* __restrict__ resid,
    float* __restrict__ out, int M, int N, int K)
{
    __shared__ float As[16][64];   // [k][m]
    __shared__ float Bs[16][64];   // [k][n]

    const int t  = threadIdx.x;
    const int m0 = blockIdx.y * 64;
    const int n0 = blockIdx.x * 64;
    const int tx = t & 15;
    const int ty = t >> 4;

    const int am = t >> 2;           // 0..63
    const int ak = (t & 3) << 2;     // 0,4,8,12
    const int bk = t >> 4;           // 0..15
    const int bn = (t & 15) << 2;    // 0..60

    const float* Xp = X + (size_t)(m0 + am) * K + ak;
    const float* Wp = W + (size_t)bk * N + n0 + bn;

    float acc[4][4] = {};

    for (int k0 = 0; k0 < K; k0 += 16) {
        const float4 a4 = *reinterpret_cast<const float4*>(Xp + k0);
        const float4 b4 = *reinterpret_cast<const float4*>(Wp + (size_t)k0 * N);
        As[ak + 0][am] = a4.x;
        As[ak + 1][am] = a4.y;
        As[ak + 2][am] = a4.z;
        As[ak + 3][am] = a4.w;
        *reinterpret_cast<float4*>(&Bs[bk][bn]) = b4;
        __syncthreads();
#pragma unroll
        for (int kk = 0; kk < 16; ++kk) {
            const float4 av = *reinterpret_cast<const float4*>(&As[kk][ty * 4]);
            const float4 bv = *reinterpret_cast<const float4*>(&Bs[kk][tx * 4]);
            acc[0][0] += av.x * bv.x; acc[0][1] += av.x * bv.y; acc[0][2] += av.x * bv.z; acc[0][3] += av.x * bv.w;
            acc[1][0] += av.y * bv.x; acc[1][1] += av.y * bv.y; acc[1][2] += av.y * bv.z; acc[1][3] += av.y * bv.w;
            acc[2][0] += av.z * bv.x; acc[2][1] += av.z * bv.y; acc[2][2] += av.z * bv.z; acc[2][3] += av.z * bv.w;
            acc[3][0] += av.w * bv.x; acc[3][1] += av.w * bv.y; acc[3][2] += av.w * bv.z; acc[3][3] += av.w * bv.w;
        }
        __syncthreads();
    }

#pragma unroll
    for (int i = 0; i < 4; ++i) {
        const int m = m0 + ty * 4 + i;
#pragma unroll
        for (int j = 0; j < 4; ++j) {
            const int n = n0 + tx * 4 + j;
            float v = acc[i][j] + bias[n];
            if (resid) v += resid[(size_t)m * N + n];
            if (HEADED) {
                const int b  = m >> 10;   // m / S_
                const int s  = m & 1023;
                const int h  = n >> 6;    // n / DK_
                const int dk = n & 63;
                out[(((size_t)b * H_ + h) * S_ + s) * DK_ + dk] = v;
            } else {
                out[(size_t)m * N + n] = v;
            }
        }
    }
}

// ---------------------------------------------------------------------------
// Flash-style strictly-causal attention with additive state_weight.
// One block = one (b,h) x 32-row q-tile. 256 threads: thread t owns
// row r=t/8, dk-slice (t%8)*8..+7, and score cols {g, g+8, g+16, g+24}.
// ---------------------------------------------------------------------------
__global__ __launch_bounds__(256) void attn32(
    const float* __restrict__ Qh, const float* __restrict__ Kh,
    const float* __restrict__ Vh, const float* __restrict__ SW,
    float* __restrict__ ctx)
{
    __shared__ float Qs[32][68];
    __shared__ float Ks[32][68];
    __shared__ float Vs[32][68];
    __shared__ float Ps[32][33];

    const int t  = threadIdx.x;
    const int bh = blockIdx.y;      // b*H + h
    const int b  = bh >> 4;
    const int h  = bh & 15;
    const int q0 = blockIdx.x << 5;
    const int r  = t >> 3;          // 0..31
    const int g  = t & 7;           // 0..7

    // load Q tile (32x64): 512 float4s, 2 per thread
    {
        const float* Qb = Qh + ((size_t)bh * S_ + q0) * DK_;
#pragma unroll
        for (int i = 0; i < 2; ++i) {
            const int idx = t + i * 256;
            const int row = idx >> 4, c4 = (idx & 15) << 2;
            *reinterpret_cast<float4*>(&Qs[row][c4]) =
                *reinterpret_cast<const float4*>(&Qb[row * DK_ + c4]);
        }
    }

    float acc[8] = {0.f, 0.f, 0.f, 0.f, 0.f, 0.f, 0.f, 0.f};
    float mrow = -1e30f, lrow = 0.f;

    const float* swrow = SW + ((size_t)h * S_ + (q0 + r)) * S_;
    const float* Kb = Kh + (size_t)bh * S_ * DK_;
    const float* Vb = Vh + (size_t)bh * S_ * DK_;

    const int ntiles = blockIdx.x + 1;     // causal: k-tiles 0..q0/32
    for (int tile = 0; tile < ntiles; ++tile) {
        const int k0 = tile << 5;
        __syncthreads();   // protect Ks/Vs from previous iter readers; also Qs first iter
#pragma unroll
        for (int i = 0; i < 2; ++i) {
            const int idx = t + i * 256;
            const int row = idx >> 4, c4 = (idx & 15) << 2;
            *reinterpret_cast<float4*>(&Ks[row][c4]) =
                *reinterpret_cast<const float4*>(&Kb[(size_t)(k0 + row) * DK_ + c4]);
            *reinterpret_cast<float4*>(&Vs[row][c4]) =
                *reinterpret_cast<const float4*>(&Vb[(size_t)(k0 + row) * DK_ + c4]);
        }
        __syncthreads();

        // scores: 4 cols per thread
        float sc[4] = {0.f, 0.f, 0.f, 0.f};
#pragma unroll
        for (int d4 = 0; d4 < 16; ++d4) {
            const float4 qv = *reinterpret_cast<const float4*>(&Qs[r][d4 << 2]);
#pragma unroll
            for (int j = 0; j < 4; ++j) {
                const float4 kv = *reinterpret_cast<const float4*>(&Ks[g + (j << 3)][d4 << 2]);
                sc[j] += qv.x * kv.x + qv.y * kv.y + qv.z * kv.z + qv.w * kv.w;
            }
        }

        float tmax = -1e30f;
        bool vld[4];
#pragma unroll
        for (int j = 0; j < 4; ++j) {
            const int c = g + (j << 3);
            vld[j] = (k0 + c) < (q0 + r);                    // strictly causal
            sc[j]  = vld[j] ? sc[j] * 0.125f + swrow[k0 + c] : -1e30f;
            tmax = fmaxf(tmax, sc[j]);
        }
#pragma unroll
        for (int w = 1; w < 8; w <<= 1) tmax = fmaxf(tmax, __shfl_xor(tmax, w, 64));

        const float mnew = fmaxf(mrow, tmax);
        const float corr = __expf(mrow - mnew);
        float p[4], psum = 0.f;
#pragma unroll
        for (int j = 0; j < 4; ++j) {
            p[j] = vld[j] ? __expf(sc[j] - mnew) : 0.f;
            psum += p[j];
        }
#pragma unroll
        for (int w = 1; w < 8; w <<= 1) psum += __shfl_xor(psum, w, 64);

        lrow = lrow * corr + psum;
        mrow = mnew;
#pragma unroll
        for (int jj = 0; jj < 8; ++jj) acc[jj] *= corr;

#pragma unroll
        for (int j = 0; j < 4; ++j) Ps[r][g + (j << 3)] = p[j];
        // Ps row r written & read only by lanes r*8..r*8+7 (same wave): no barrier needed.

#pragma unroll 8
        for (int c = 0; c < 32; ++c) {
            const float pv = Ps[r][c];
            const float4 va = *reinterpret_cast<const float4*>(&Vs[c][(g << 3)]);
            const float4 vb = *reinterpret_cast<const float4*>(&Vs[c][(g << 3) + 4]);
            acc[0] += pv * va.x; acc[1] += pv * va.y; acc[2] += pv * va.z; acc[3] += pv * va.w;
            acc[4] += pv * vb.x; acc[5] += pv * vb.y; acc[6] += pv * vb.z; acc[7] += pv * vb.w;
        }
    }

    const float inv = (lrow > 0.f) ? 1.f / lrow : 0.f;   // fully-masked row (q=0) -> zeros
    float4 o0, o1;
    o0.x = acc[0] * inv; o0.y = acc[1] * inv; o0.z = acc[2] * inv; o0.w = acc[3] * inv;
    o1.x = acc[4] * inv; o1.y = acc[5] * inv; o1.z = acc[6] * inv; o1.w = acc[7] * inv;
    float* orow = ctx + ((size_t)(b * S_ + q0 + r)) * D_ + h * DK_ + (g << 3);
    *reinterpret_cast<float4*>(orow)     = o0;
    *reinterpret_cast<float4*>(orow + 4) = o1;
}

// ---------------------------------------------------------------------------
// LayerNorm over last dim (1024). One block per row, 256 threads, float4.
// ---------------------------------------------------------------------------
__global__ __launch_bounds__(256) void layernorm_k(
    const float* __restrict__ x, const float* __restrict__ gamma,
    const float* __restrict__ beta, float* __restrict__ out)
{
    const int row = blockIdx.x;
    const int t   = threadIdx.x;
    const float4 v = *reinterpret_cast<const float4*>(&x[(size_t)row * D_ + (t << 2)]);
    float sum = v.x + v.y + v.z + v.w;
    float sq  = v.x * v.x + v.y * v.y + v.z * v.z + v.w * v.w;
#pragma unroll
    for (int w = 1; w < 64; w <<= 1) {
        sum += __shfl_xor(sum, w, 64);
        sq  += __shfl_xor(sq,  w, 64);
    }
    __shared__ float red[8];
    const int wid = t >> 6;
    if ((t & 63) == 0) { red[wid] = sum; red[wid + 4] = sq; }
    __syncthreads();
    sum = red[0] + red[1] + red[2] + red[3];
    sq  = red[4] + red[5] + red[6] + red[7];
    const float mu  = sum * (1.f / 1024.f);
    const float var = sq * (1.f / 1024.f) - mu * mu;
    const float rs  = rsqrtf(var + 1e-5f);
    const float4 gm = *reinterpret_cast<const float4*>(&gamma[t << 2]);
    const float4 bt = *reinterpret_cast<const float4*>(&beta[t << 2]);
    float4 o;
    o.x = (v.x - mu) * rs * gm.x + bt.x;
    o.y = (v.y - mu) * rs * gm.y + bt.y;
    o.z = (v.z - mu) * rs * gm.z + bt.z;
    o.w = (v.w - mu) * rs * gm.w + bt.w;
    *reinterpret_cast<float4*>(&out[(size_t)row * D_ + (t << 2)]) = o;
}

// ---------------------------------------------------------------------------
extern "C" void kernel_launch(void* const* d_in, const int* in_sizes, int n_in,
                              void* d_out, int out_size, void* d_ws, size_t ws_size,
                              hipStream_t stream)
{
    const float* query  = (const float*)d_in[0];
    const float* key    = (const float*)d_in[1];
    const float* values = (const float*)d_in[2];
    // d_in[3] = lens : unused by the reference
    const float* SW     = (const float*)d_in[4];
    const float* Wq     = (const float*)d_in[5];
    const float* bq     = (const float*)d_in[6];
    const float* Wv     = (const float*)d_in[7];
    const float* bv     = (const float*)d_in[8];
    const float* Wo     = (const float*)d_in[9];
    const float* bo     = (const float*)d_in[10];
    const float* gamma  = (const float*)d_in[11];
    const float* beta   = (const float*)d_in[12];

    float* ws = (float*)d_ws;
    const size_t SEG = (size_t)B_ * H_ * S_ * DK_;   // 4,194,304 floats = 16 MB
    float* Qh   = ws;
    float* Kh   = ws + SEG;
    float* Vh   = ws + 2 * SEG;
    float* ctx  = ws + 3 * SEG;
    float* xbuf = ws;                 // reuse Qh segment after attention

    const dim3 blk(256);
    const dim3 gg(16, 64);            // N/64, M/64

    gemm64<1><<<gg, blk, 0, stream>>>(query,  Wq, bq, nullptr, Qh, 4096, 1024, 1024);
    gemm64<1><<<gg, blk, 0, stream>>>(key,    Wq, bq, nullptr, Kh, 4096, 1024, 1024);  // kq_same
    gemm64<1><<<gg, blk, 0, stream>>>(values, Wv, bv, nullptr, Vh, 4096, 1024, 1024);

    attn32<<<dim3(32, 64), blk, 0, stream>>>(Qh, Kh, Vh, SW, ctx);

    gemm64<0><<<gg, blk, 0, stream>>>(ctx, Wo, bo, query, xbuf, 4096, 1024, 1024);

    layernorm_k<<<dim3(4096), blk, 0, stream>>>(xbuf, gamma, beta, (float*)d_out);
}

// Round 2
// 572.781 us; speedup vs baseline: 2.2146x; 2.2146x over previous
//
#include <hip/hip_runtime.h>
#include <math.h>

#define B_ 4
#define S_ 1024
#define D_ 1024
#define H_ 16
#define DK_ 64

typedef __attribute__((ext_vector_type(8))) short short8;
typedef __attribute__((ext_vector_type(16))) float f32x16;

static __device__ __forceinline__ unsigned bf16rne(float x) {
    unsigned b = __float_as_uint(x);
    return (b + 0x7FFFu + ((b >> 16) & 1u)) >> 16;
}

// ---------------------------------------------------------------------------
// Tiled fp32 GEMM: C[M,N] = X[M,K] @ W[K,N] + bias (+ resid).
// MODE 0: fp32 flat out. MODE 1: bf16 headed [bh][S][DK]. MODE 2: bf16 [bh][DK][S].
// ---------------------------------------------------------------------------
template<int MODE>
__global__ __launch_bounds__(256) void gemm64(
    const float* __restrict__ X, const float* __restrict__ W,
    const float* __restrict__ bias, const float* __restrict__ resid,
    void* __restrict__ outp, int M, int N, int K)
{
    __shared__ float As[16][64];   // [k][m]
    __shared__ float Bs[16][64];   // [k][n]

    const int t  = threadIdx.x;
    const int m0 = blockIdx.y * 64;
    const int n0 = blockIdx.x * 64;
    const int tx = t & 15;
    const int ty = t >> 4;

    const int am = t >> 2;
    const int ak = (t & 3) << 2;
    const int bk = t >> 4;
    const int bn = (t & 15) << 2;

    const float* Xp = X + (size_t)(m0 + am) * K + ak;
    const float* Wp = W + (size_t)bk * N + n0 + bn;

    float acc[4][4] = {};

    for (int k0 = 0; k0 < K; k0 += 16) {
        const float4 a4 = *reinterpret_cast<const float4*>(Xp + k0);
        const float4 b4 = *reinterpret_cast<const float4*>(Wp + (size_t)k0 * N);
        As[ak + 0][am] = a4.x;
        As[ak + 1][am] = a4.y;
        As[ak + 2][am] = a4.z;
        As[ak + 3][am] = a4.w;
        *reinterpret_cast<float4*>(&Bs[bk][bn]) = b4;
        __syncthreads();
#pragma unroll
        for (int kk = 0; kk < 16; ++kk) {
            const float4 av = *reinterpret_cast<const float4*>(&As[kk][ty * 4]);
            const float4 bv = *reinterpret_cast<const float4*>(&Bs[kk][tx * 4]);
            acc[0][0] += av.x * bv.x; acc[0][1] += av.x * bv.y; acc[0][2] += av.x * bv.z; acc[0][3] += av.x * bv.w;
            acc[1][0] += av.y * bv.x; acc[1][1] += av.y * bv.y; acc[1][2] += av.y * bv.z; acc[1][3] += av.y * bv.w;
            acc[2][0] += av.z * bv.x; acc[2][1] += av.z * bv.y; acc[2][2] += av.z * bv.z; acc[2][3] += av.z * bv.w;
            acc[3][0] += av.w * bv.x; acc[3][1] += av.w * bv.y; acc[3][2] += av.w * bv.z; acc[3][3] += av.w * bv.w;
        }
        __syncthreads();
    }

#pragma unroll
    for (int i = 0; i < 4; ++i) {
        const int m = m0 + ty * 4 + i;
#pragma unroll
        for (int j = 0; j < 4; ++j) {
            const int n = n0 + tx * 4 + j;
            float v = acc[i][j] + bias[n];
            if (resid) v += resid[(size_t)m * N + n];
            if (MODE == 0) {
                ((float*)outp)[(size_t)m * N + n] = v;
            } else {
                const int b  = m >> 10;
                const int s  = m & 1023;
                const int h  = n >> 6;
                const int dk = n & 63;
                ushort* o = (ushort*)outp;
                if (MODE == 1)
                    o[(((size_t)b * H_ + h) * S_ + s) * DK_ + dk] = (ushort)bf16rne(v);
                else
                    o[(((size_t)b * H_ + h) * DK_ + dk) * S_ + s] = (ushort)bf16rne(v);
            }
        }
    }
}

// ---------------------------------------------------------------------------
// MFMA bf16 flash attention, swapped-operand form.
// Block = 4 waves x 32 q-rows = 128 q-rows of one (b,h). K-tile = 32 keys.
// Swapped QK^T: S^T[key][q] = K·Q^T  -> lane owns q-row (lane&31); softmax
// state fully lane-local. PV as ctx^T = V^T·P^T keeps acc lane-local too.
// ---------------------------------------------------------------------------
__global__ __launch_bounds__(256) void attn_mfma(
    const ushort* __restrict__ Qh, const ushort* __restrict__ Kh,
    const ushort* __restrict__ Vt, const float* __restrict__ SW,
    float* __restrict__ ctx)
{
    __shared__ ushort Ks[32][68];   // 32 keys x 64 dk, pad->2-way banks (free)
    __shared__ ushort Vs[64][36];   // 64 dk x 32 keys, pad->2-way banks

    const int t    = threadIdx.x;
    const int lane = t & 63;
    const int w    = t >> 6;                 // wave 0..3
    const int bid  = blockIdx.x;             // 0..511
    const int bh   = bid & 63;
    const int b    = bh >> 4;
    const int h    = bh & 15;
    int qb = bid >> 6;                       // 0..7
    qb = (qb < 4) ? qb : 11 - qb;            // pair heavy/light q-blocks per CU

    const int ql  = lane & 31;               // q-row within wave tile (and key idx for A-frags)
    const int hi  = lane >> 5;
    const int q0w = qb * 128 + w * 32;
    const int qt  = 4 * qb + w;              // this wave's q-tile index
    const int maxt = 4 * qb + 4;             // k-tiles the block must stage

    const ushort* Qg  = Qh + ((size_t)bh * S_ + q0w) * DK_;
    const ushort* Kg  = Kh + (size_t)bh * S_ * DK_;
    const ushort* Vg  = Vt + (size_t)bh * DK_ * S_;
    const float*  swp = SW + ((size_t)h * S_ + q0w + ql) * S_;
    const int qglob = q0w + ql;

    // Q fragments: lane holds Q[q=ql][dk = c*16 + hi*8 + i], i=0..7
    short8 qf[4];
#pragma unroll
    for (int c = 0; c < 4; ++c) {
        union { int4 i; short8 s; } u;
        u.i = *reinterpret_cast<const int4*>(&Qg[(size_t)ql * DK_ + c * 16 + hi * 8]);
        qf[c] = u.s;
    }

    f32x16 accA, accB;
#pragma unroll
    for (int r = 0; r < 16; ++r) { accA[r] = 0.f; accB[r] = 0.f; }
    float mrow = -1e30f, lrow = 0.f;

    for (int kt = 0; kt < maxt; ++kt) {
        const int k0 = kt << 5;
        __syncthreads();                      // prev compute done before restage
        {   // stage K tile: 32 rows x 128B; thread t: row t>>3, 16B chunk t&7
            const int r = t >> 3, c = t & 7;
            union { int4 i; int2 p[2]; } u;
            u.i = *reinterpret_cast<const int4*>(&Kg[(size_t)(k0 + r) * DK_ + c * 8]);
            *reinterpret_cast<int2*>(&Ks[r][c * 8])     = u.p[0];
            *reinterpret_cast<int2*>(&Ks[r][c * 8 + 4]) = u.p[1];
        }
        {   // stage V^T tile: 64 rows x 64B; thread t: row t>>2, 16B chunk t&3
            const int r = t >> 2, c = t & 3;
            union { int4 i; int2 p[2]; } u;
            u.i = *reinterpret_cast<const int4*>(&Vg[(size_t)r * S_ + k0 + c * 8]);
            *reinterpret_cast<int2*>(&Vs[r][c * 8])     = u.p[0];
            *reinterpret_cast<int2*>(&Vs[r][c * 8 + 4]) = u.p[1];
        }
        __syncthreads();
        if (kt > qt) continue;                // causal: this wave done with MFMA work

        // state_weight: full-line float4 gathers (keys base k0 + g*8 + hi*4)
        const float4 sw0 = *reinterpret_cast<const float4*>(&swp[k0 +  0 + hi * 4]);
        const float4 sw1 = *reinterpret_cast<const float4*>(&swp[k0 +  8 + hi * 4]);
        const float4 sw2 = *reinterpret_cast<const float4*>(&swp[k0 + 16 + hi * 4]);
        const float4 sw3 = *reinterpret_cast<const float4*>(&swp[k0 + 24 + hi * 4]);

        // QK^T (swapped): sc[r] = S^T[key=crow(r,hi)][q=ql]
        f32x16 sc;
#pragma unroll
        for (int r = 0; r < 16; ++r) sc[r] = 0.f;
#pragma unroll
        for (int c = 0; c < 4; ++c) {
            union { int2 p[2]; short8 s; } u;
            u.p[0] = *reinterpret_cast<const int2*>(&Ks[ql][c * 16 + hi * 8]);
            u.p[1] = *reinterpret_cast<const int2*>(&Ks[ql][c * 16 + hi * 8 + 4]);
            sc = __builtin_amdgcn_mfma_f32_32x32x16_bf16(u.s, qf[c], sc, 0, 0, 0);
        }

        float swv[16] = { sw0.x, sw0.y, sw0.z, sw0.w, sw1.x, sw1.y, sw1.z, sw1.w,
                          sw2.x, sw2.y, sw2.z, sw2.w, sw3.x, sw3.y, sw3.z, sw3.w };
        float p[16];
        float tmax = -1e30f;
#pragma unroll
        for (int r = 0; r < 16; ++r) {
            const int key = k0 + (r & 3) + ((r >> 2) << 3) + (hi << 2);
            const float s = (key < qglob) ? sc[r] * 0.125f + swv[r] : -1e30f;
            p[r] = s;
            tmax = fmaxf(tmax, s);
        }
        tmax = fmaxf(tmax, __shfl_xor(tmax, 32, 64));
        const float mnew = fmaxf(mrow, tmax);
        const float corr = __expf(mrow - mnew);
        float psum = 0.f;
#pragma unroll
        for (int r = 0; r < 16; ++r) {
            const float e = (p[r] > -1e29f) ? __expf(p[r] - mnew) : 0.f;
            p[r] = e;
            psum += e;
        }
        psum += __shfl_xor(psum, 32, 64);
        lrow = lrow * corr + psum;
        mrow = mnew;
#pragma unroll
        for (int r = 0; r < 16; ++r) { accA[r] *= corr; accB[r] *= corr; }

        // pack P -> bf16 pairs; redistribute to PV B-fragment layout
        unsigned pk[8];
#pragma unroll
        for (int j = 0; j < 8; ++j)
            pk[j] = bf16rne(p[2 * j]) | (bf16rne(p[2 * j + 1]) << 16);

        unsigned x0 = (unsigned)__shfl_xor((int)pk[0], 32, 64);
        unsigned x1 = (unsigned)__shfl_xor((int)pk[1], 32, 64);
        unsigned x2 = (unsigned)__shfl_xor((int)pk[2], 32, 64);
        unsigned x3 = (unsigned)__shfl_xor((int)pk[3], 32, 64);
        unsigned x4 = (unsigned)__shfl_xor((int)pk[4], 32, 64);
        unsigned x5 = (unsigned)__shfl_xor((int)pk[5], 32, 64);
        unsigned x6 = (unsigned)__shfl_xor((int)pk[6], 32, 64);
        unsigned x7 = (unsigned)__shfl_xor((int)pk[7], 32, 64);

        union { unsigned u[4]; short8 s; } pa0, pa1;
        pa0.u[0] = hi ? x2 : pk[0];
        pa0.u[1] = hi ? x3 : pk[1];
        pa0.u[2] = hi ? pk[2] : x0;
        pa0.u[3] = hi ? pk[3] : x1;
        pa1.u[0] = hi ? x6 : pk[4];
        pa1.u[1] = hi ? x7 : pk[5];
        pa1.u[2] = hi ? pk[6] : x4;
        pa1.u[3] = hi ? pk[7] : x5;

        // PV (swapped): acc[dk][q] += V^T · P^T ; A-frag = Vs rows (contiguous)
#pragma unroll
        for (int cc = 0; cc < 2; ++cc) {
            const short8 pb = cc ? pa1.s : pa0.s;
            union { int2 p[2]; short8 s; } va, vb;
            va.p[0] = *reinterpret_cast<const int2*>(&Vs[ql][cc * 16 + hi * 8]);
            va.p[1] = *reinterpret_cast<const int2*>(&Vs[ql][cc * 16 + hi * 8 + 4]);
            vb.p[0] = *reinterpret_cast<const int2*>(&Vs[ql + 32][cc * 16 + hi * 8]);
            vb.p[1] = *reinterpret_cast<const int2*>(&Vs[ql + 32][cc * 16 + hi * 8 + 4]);
            accA = __builtin_amdgcn_mfma_f32_32x32x16_bf16(va.s, pb, accA, 0, 0, 0);
            accB = __builtin_amdgcn_mfma_f32_32x32x16_bf16(vb.s, pb, accB, 0, 0, 0);
        }
    }

    // epilogue: lane owns q-row ql; acc[r] = ctx[q][dk = crow(r,hi) (+32)]
    const float inv = (lrow > 0.f) ? 1.f / lrow : 0.f;   // fully-masked row 0 -> zeros
    float* crow_ = ctx + ((size_t)b * S_ + q0w + ql) * D_ + h * DK_;
#pragma unroll
    for (int g = 0; g < 4; ++g) {
        float4 oA, oB;
        oA.x = accA[4 * g + 0] * inv; oA.y = accA[4 * g + 1] * inv;
        oA.z = accA[4 * g + 2] * inv; oA.w = accA[4 * g + 3] * inv;
        oB.x = accB[4 * g + 0] * inv; oB.y = accB[4 * g + 1] * inv;
        oB.z = accB[4 * g + 2] * inv; oB.w = accB[4 * g + 3] * inv;
        *reinterpret_cast<float4*>(&crow_[g * 8 + hi * 4])      = oA;
        *reinterpret_cast<float4*>(&crow_[g * 8 + hi * 4 + 32]) = oB;
    }
}

// ---------------------------------------------------------------------------
// LayerNorm over last dim (1024). One block per row, 256 threads, float4.
// ---------------------------------------------------------------------------
__global__ __launch_bounds__(256) void layernorm_k(
    const float* __restrict__ x, const float* __restrict__ gamma,
    const float* __restrict__ beta, float* __restrict__ out)
{
    const int row = blockIdx.x;
    const int t   = threadIdx.x;
    const float4 v = *reinterpret_cast<const float4*>(&x[(size_t)row * D_ + (t << 2)]);
    float sum = v.x + v.y + v.z + v.w;
    float sq  = v.x * v.x + v.y * v.y + v.z * v.z + v.w * v.w;
#pragma unroll
    for (int w = 1; w < 64; w <<= 1) {
        sum += __shfl_xor(sum, w, 64);
        sq  += __shfl_xor(sq,  w, 64);
    }
    __shared__ float red[8];
    const int wid = t >> 6;
    if ((t & 63) == 0) { red[wid] = sum; red[wid + 4] = sq; }
    __syncthreads();
    sum = red[0] + red[1] + red[2] + red[3];
    sq  = red[4] + red[5] + red[6] + red[7];
    const float mu  = sum * (1.f / 1024.f);
    const float var = sq * (1.f / 1024.f) - mu * mu;
    const float rs  = rsqrtf(var + 1e-5f);
    const float4 gm = *reinterpret_cast<const float4*>(&gamma[t << 2]);
    const float4 bt = *reinterpret_cast<const float4*>(&beta[t << 2]);
    float4 o;
    o.x = (v.x - mu) * rs * gm.x + bt.x;
    o.y = (v.y - mu) * rs * gm.y + bt.y;
    o.z = (v.z - mu) * rs * gm.z + bt.z;
    o.w = (v.w - mu) * rs * gm.w + bt.w;
    *reinterpret_cast<float4*>(&out[(size_t)row * D_ + (t << 2)]) = o;
}

// ---------------------------------------------------------------------------
extern "C" void kernel_launch(void* const* d_in, const int* in_sizes, int n_in,
                              void* d_out, int out_size, void* d_ws, size_t ws_size,
                              hipStream_t stream)
{
    const float* query  = (const float*)d_in[0];
    const float* key    = (const float*)d_in[1];
    const float* values = (const float*)d_in[2];
    // d_in[3] = lens : unused by the reference
    const float* SW     = (const float*)d_in[4];
    const float* Wq     = (const float*)d_in[5];
    const float* bq     = (const float*)d_in[6];
    const float* Wv     = (const float*)d_in[7];
    const float* bv     = (const float*)d_in[8];
    const float* Wo     = (const float*)d_in[9];
    const float* bo     = (const float*)d_in[10];
    const float* gamma  = (const float*)d_in[11];
    const float* beta   = (const float*)d_in[12];

    char* ws = (char*)d_ws;
    ushort* Qh  = (ushort*)(ws);                          //  8 MB bf16 [bh][S][DK]
    ushort* Kh  = (ushort*)(ws + (size_t)8  * 1024 * 1024);
    ushort* Vtb = (ushort*)(ws + (size_t)16 * 1024 * 1024); // bf16 [bh][DK][S]
    float*  ctx = (float*) (ws + (size_t)24 * 1024 * 1024); // 16 MB fp32 [B*S][D]
    float*  xbf = (float*) (ws + (size_t)40 * 1024 * 1024); // 16 MB fp32

    const dim3 blk(256);
    const dim3 gg(16, 64);

    gemm64<1><<<gg, blk, 0, stream>>>(query,  Wq, bq, nullptr, Qh,  4096, 1024, 1024);
    gemm64<1><<<gg, blk, 0, stream>>>(key,    Wq, bq, nullptr, Kh,  4096, 1024, 1024);  // kq_same
    gemm64<2><<<gg, blk, 0, stream>>>(values, Wv, bv, nullptr, Vtb, 4096, 1024, 1024);

    attn_mfma<<<dim3(512), blk, 0, stream>>>(Qh, Kh, Vtb, SW, ctx);

    gemm64<0><<<gg, blk, 0, stream>>>(ctx, Wo, bo, query, xbf, 4096, 1024, 1024);

    layernorm_k<<<dim3(4096), blk, 0, stream>>>(xbf, gamma, beta, (float*)d_out);
}

// Round 3
// 194.683 us; speedup vs baseline: 6.5156x; 2.9421x over previous
//
#include <hip/hip_runtime.h>

#define B_ 4
#define S_ 1024
#define D_ 1024
#define H_ 16
#define DK_ 64

typedef __attribute__((ext_vector_type(8))) short short8;
typedef __attribute__((ext_vector_type(4))) float f32x4;
typedef __attribute__((ext_vector_type(16))) float f32x16;

static __device__ __forceinline__ unsigned bf16rne(float x) {
    unsigned b = __float_as_uint(x);
    return (b + 0x7FFFu + ((b >> 16) & 1u)) >> 16;
}

// ---------------------------------------------------------------------------
// fp32 -> bf16 convert (flat, 8 elems/thread). n must be multiple of 2048.
// ---------------------------------------------------------------------------
__global__ __launch_bounds__(256) void cvt_bf16(
    const float* __restrict__ in, ushort* __restrict__ out)
{
    const size_t i = ((size_t)blockIdx.x * 256 + threadIdx.x) * 8;
    const float4 a = *reinterpret_cast<const float4*>(in + i);
    const float4 b = *reinterpret_cast<const float4*>(in + i + 4);
    union { ushort u[8]; int4 v; } p;
    p.u[0] = (ushort)bf16rne(a.x); p.u[1] = (ushort)bf16rne(a.y);
    p.u[2] = (ushort)bf16rne(a.z); p.u[3] = (ushort)bf16rne(a.w);
    p.u[4] = (ushort)bf16rne(b.x); p.u[5] = (ushort)bf16rne(b.y);
    p.u[6] = (ushort)bf16rne(b.z); p.u[7] = (ushort)bf16rne(b.w);
    *reinterpret_cast<int4*>(out + i) = p.v;
}

// ---------------------------------------------------------------------------
// W [1024][1024] fp32 -> Wt [n][k] bf16 (transpose + convert), 32x32 tiles.
// ---------------------------------------------------------------------------
__global__ __launch_bounds__(256) void transpose_cvt(
    const float* __restrict__ W, ushort* __restrict__ Wt)
{
    __shared__ float ts[32][33];
    const int t  = threadIdx.x;
    const int k0 = blockIdx.y * 32, n0 = blockIdx.x * 32;
    const int r  = t >> 3, c4 = (t & 7) * 4;
    const float4 v = *reinterpret_cast<const float4*>(&W[(size_t)(k0 + r) * 1024 + n0 + c4]);
    ts[r][c4] = v.x; ts[r][c4 + 1] = v.y; ts[r][c4 + 2] = v.z; ts[r][c4 + 3] = v.w;
    __syncthreads();
    ushort4 o;
    o.x = (ushort)bf16rne(ts[c4    ][r]);
    o.y = (ushort)bf16rne(ts[c4 + 1][r]);
    o.z = (ushort)bf16rne(ts[c4 + 2][r]);
    o.w = (ushort)bf16rne(ts[c4 + 3][r]);
    *reinterpret_cast<ushort4*>(&Wt[(size_t)(n0 + r) * 1024 + k0 + c4]) = o;
}

// ---------------------------------------------------------------------------
// bf16 MFMA GEMM: C[4096,1024] = X[4096,1024] @ Wt^T (+bias, +resid).
// 128x128 tile, BK=64, 4 waves (2x2), 4x4 frags of 16x16x32 per wave.
// global_load_lds(16B) staging, linear LDS + inverse-swizzled source,
// XOR-swizzled ds_read_b128 (2-way = free). Double-buffered. XCD swizzle.
// MODE 0: fp32 out + resid. MODE 1: bf16 [bh][S][DK]. MODE 2: bf16 [bh][DK][S].
// ---------------------------------------------------------------------------
template<int MODE>
__global__ __launch_bounds__(256) void gemm_mfma(
    const ushort* __restrict__ X, const ushort* __restrict__ Wt,
    const float* __restrict__ bias, const float* __restrict__ resid,
    void* __restrict__ outp)
{
    __shared__ ushort As[2][128 * 64];
    __shared__ ushort Bs[2][128 * 64];

    const int t    = threadIdx.x;
    const int lane = t & 63;
    const int w    = t >> 6;

    // chunked XCD swizzle: XCD x gets 32 consecutive logical tiles
    const int logical = (blockIdx.x & 7) * 32 + (blockIdx.x >> 3);
    const int bm = logical >> 3;      // 0..31
    const int bn = logical & 7;       // 0..7

    // ---- staging source pointers (per-lane, inverse-swizzled chunk) ----
    const int srow   = lane >> 3;                 // row-in-8
    const int schunk = (lane & 7) ^ srow;         // chunk ^ (row&7)
    const ushort* ag[4];
    const ushort* bg[4];
#pragma unroll
    for (int j = 0; j < 4; ++j) {
        ag[j] = X  + (size_t)(bm * 128 + w * 32 + j * 8 + srow) * 1024 + schunk * 8;
        bg[j] = Wt + (size_t)(bn * 128 + w * 32 + j * 8 + srow) * 1024 + schunk * 8;
    }
    const int ldsoff = w * 2048;                  // w*32 rows * 64

#define STAGE(buf, k0)                                                           \
    do {                                                                         \
        _Pragma("unroll")                                                        \
        for (int j = 0; j < 4; ++j) {                                            \
            __builtin_amdgcn_global_load_lds(                                    \
                (__attribute__((address_space(1))) const void*)(ag[j] + (k0)),   \
                (__attribute__((address_space(3))) void*)&As[buf][ldsoff + j * 512], \
                16, 0, 0);                                                       \
            __builtin_amdgcn_global_load_lds(                                    \
                (__attribute__((address_space(1))) const void*)(bg[j] + (k0)),   \
                (__attribute__((address_space(3))) void*)&Bs[buf][ldsoff + j * 512], \
                16, 0, 0);                                                       \
        }                                                                        \
    } while (0)

    // ---- fragment geometry ----
    const int fr = lane & 15;                     // frag row/col
    const int fk = lane >> 4;                     // k sub-chunk
    const int wm = w >> 1, wn = w & 1;

    f32x4 acc[4][4];
#pragma unroll
    for (int m = 0; m < 4; ++m)
#pragma unroll
        for (int n = 0; n < 4; ++n) acc[m][n] = (f32x4){0.f, 0.f, 0.f, 0.f};

#define COMPUTE(buf)                                                             \
    do {                                                                         \
        _Pragma("unroll")                                                        \
        for (int ks = 0; ks < 2; ++ks) {                                         \
            short8 af[4], bfr[4];                                                \
            _Pragma("unroll")                                                    \
            for (int m = 0; m < 4; ++m)                                          \
                af[m] = *reinterpret_cast<const short8*>(                        \
                    &As[buf][(wm * 64 + m * 16 + fr) * 64 +                      \
                             (((ks * 4 + fk) ^ (fr & 7)) * 8)]);                 \
            _Pragma("unroll")                                                    \
            for (int n = 0; n < 4; ++n)                                          \
                bfr[n] = *reinterpret_cast<const short8*>(                       \
                    &Bs[buf][(wn * 64 + n * 16 + fr) * 64 +                      \
                             (((ks * 4 + fk) ^ (fr & 7)) * 8)]);                 \
            _Pragma("unroll")                                                    \
            for (int m = 0; m < 4; ++m)                                          \
                _Pragma("unroll")                                                \
                for (int n = 0; n < 4; ++n)                                      \
                    acc[m][n] = __builtin_amdgcn_mfma_f32_16x16x32_bf16(         \
                        af[m], bfr[n], acc[m][n], 0, 0, 0);                      \
        }                                                                        \
    } while (0)

    STAGE(0, 0);
#pragma unroll 1
    for (int kt = 0; kt < 16; kt += 2) {
        __syncthreads();                       // drains stage(kt), prev reads done
        if (kt + 1 < 16) STAGE(1, (kt + 1) * 64);
        COMPUTE(0);
        __syncthreads();
        if (kt + 2 < 16) STAGE(0, (kt + 2) * 64);
        COMPUTE(1);
    }
#undef STAGE
#undef COMPUTE

    // ---- epilogue: C row = A row, col = B col; row=(lane>>4)*4+j, col=lane&15
#pragma unroll
    for (int m = 0; m < 4; ++m) {
        const int row0 = bm * 128 + wm * 64 + m * 16 + fk * 4;
#pragma unroll
        for (int n = 0; n < 4; ++n) {
            const int col = bn * 128 + wn * 64 + n * 16 + fr;
            const float bc = bias[col];
            if (MODE == 0) {
                float* o = (float*)outp;
#pragma unroll
                for (int j = 0; j < 4; ++j) {
                    const int row = row0 + j;
                    o[(size_t)row * 1024 + col] =
                        acc[m][n][j] + bc + resid[(size_t)row * 1024 + col];
                }
            } else if (MODE == 1) {
                ushort* o = (ushort*)outp;
                const int b_ = row0 >> 10, s0 = row0 & 1023;
                const int h  = col >> 6,   dk = col & 63;
#pragma unroll
                for (int j = 0; j < 4; ++j)
                    o[(((size_t)b_ * H_ + h) * S_ + s0 + j) * DK_ + dk] =
                        (ushort)bf16rne(acc[m][n][j] + bc);
            } else {
                ushort* o = (ushort*)outp;
                const int b_ = row0 >> 10, s0 = row0 & 1023;
                const int h  = col >> 6,   dk = col & 63;
                ushort4 pk;
                pk.x = (ushort)bf16rne(acc[m][n][0] + bc);
                pk.y = (ushort)bf16rne(acc[m][n][1] + bc);
                pk.z = (ushort)bf16rne(acc[m][n][2] + bc);
                pk.w = (ushort)bf16rne(acc[m][n][3] + bc);
                *reinterpret_cast<ushort4*>(
                    &o[(((size_t)b_ * H_ + h) * DK_ + dk) * S_ + s0]) = pk;
            }
        }
    }
}

// ---------------------------------------------------------------------------
// MFMA bf16 flash attention, swapped-operand form (unchanged from R2 except
// bf16 ctx output). Block = 4 waves x 32 q-rows of one (b,h).
// ---------------------------------------------------------------------------
__global__ __launch_bounds__(256) void attn_mfma(
    const ushort* __restrict__ Qh, const ushort* __restrict__ Kh,
    const ushort* __restrict__ Vt, const float* __restrict__ SW,
    ushort* __restrict__ ctx)
{
    __shared__ ushort Ks[32][68];
    __shared__ ushort Vs[64][36];

    const int t    = threadIdx.x;
    const int lane = t & 63;
    const int w    = t >> 6;
    const int bid  = blockIdx.x;
    const int bh   = bid & 63;
    const int b    = bh >> 4;
    const int h    = bh & 15;
    int qb = bid >> 6;
    qb = (qb < 4) ? qb : 11 - qb;

    const int ql  = lane & 31;
    const int hi  = lane >> 5;
    const int q0w = qb * 128 + w * 32;
    const int qt  = 4 * qb + w;
    const int maxt = 4 * qb + 4;

    const ushort* Qg  = Qh + ((size_t)bh * S_ + q0w) * DK_;
    const ushort* Kg  = Kh + (size_t)bh * S_ * DK_;
    const ushort* Vg  = Vt + (size_t)bh * DK_ * S_;
    const float*  swp = SW + ((size_t)h * S_ + q0w + ql) * S_;
    const int qglob = q0w + ql;

    short8 qf[4];
#pragma unroll
    for (int c = 0; c < 4; ++c) {
        union { int4 i; short8 s; } u;
        u.i = *reinterpret_cast<const int4*>(&Qg[(size_t)ql * DK_ + c * 16 + hi * 8]);
        qf[c] = u.s;
    }

    f32x16 accA, accB;
#pragma unroll
    for (int r = 0; r < 16; ++r) { accA[r] = 0.f; accB[r] = 0.f; }
    float mrow = -1e30f, lrow = 0.f;

    for (int kt = 0; kt < maxt; ++kt) {
        const int k0 = kt << 5;
        __syncthreads();
        {
            const int r = t >> 3, c = t & 7;
            union { int4 i; int2 p[2]; } u;
            u.i = *reinterpret_cast<const int4*>(&Kg[(size_t)(k0 + r) * DK_ + c * 8]);
            *reinterpret_cast<int2*>(&Ks[r][c * 8])     = u.p[0];
            *reinterpret_cast<int2*>(&Ks[r][c * 8 + 4]) = u.p[1];
        }
        {
            const int r = t >> 2, c = t & 3;
            union { int4 i; int2 p[2]; } u;
            u.i = *reinterpret_cast<const int4*>(&Vg[(size_t)r * S_ + k0 + c * 8]);
            *reinterpret_cast<int2*>(&Vs[r][c * 8])     = u.p[0];
            *reinterpret_cast<int2*>(&Vs[r][c * 8 + 4]) = u.p[1];
        }
        __syncthreads();
        if (kt > qt) continue;

        const float4 sw0 = *reinterpret_cast<const float4*>(&swp[k0 +  0 + hi * 4]);
        const float4 sw1 = *reinterpret_cast<const float4*>(&swp[k0 +  8 + hi * 4]);
        const float4 sw2 = *reinterpret_cast<const float4*>(&swp[k0 + 16 + hi * 4]);
        const float4 sw3 = *reinterpret_cast<const float4*>(&swp[k0 + 24 + hi * 4]);

        f32x16 sc;
#pragma unroll
        for (int r = 0; r < 16; ++r) sc[r] = 0.f;
#pragma unroll
        for (int c = 0; c < 4; ++c) {
            union { int2 p[2]; short8 s; } u;
            u.p[0] = *reinterpret_cast<const int2*>(&Ks[ql][c * 16 + hi * 8]);
            u.p[1] = *reinterpret_cast<const int2*>(&Ks[ql][c * 16 + hi * 8 + 4]);
            sc = __builtin_amdgcn_mfma_f32_32x32x16_bf16(u.s, qf[c], sc, 0, 0, 0);
        }

        float swv[16] = { sw0.x, sw0.y, sw0.z, sw0.w, sw1.x, sw1.y, sw1.z, sw1.w,
                          sw2.x, sw2.y, sw2.z, sw2.w, sw3.x, sw3.y, sw3.z, sw3.w };
        float p[16];
        float tmax = -1e30f;
#pragma unroll
        for (int r = 0; r < 16; ++r) {
            const int key = k0 + (r & 3) + ((r >> 2) << 3) + (hi << 2);
            const float s = (key < qglob) ? sc[r] * 0.125f + swv[r] : -1e30f;
            p[r] = s;
            tmax = fmaxf(tmax, s);
        }
        tmax = fmaxf(tmax, __shfl_xor(tmax, 32, 64));
        const float mnew = fmaxf(mrow, tmax);
        const float corr = __expf(mrow - mnew);
        float psum = 0.f;
#pragma unroll
        for (int r = 0; r < 16; ++r) {
            const float e = (p[r] > -1e29f) ? __expf(p[r] - mnew) : 0.f;
            p[r] = e;
            psum += e;
        }
        psum += __shfl_xor(psum, 32, 64);
        lrow = lrow * corr + psum;
        mrow = mnew;
#pragma unroll
        for (int r = 0; r < 16; ++r) { accA[r] *= corr; accB[r] *= corr; }

        unsigned pk[8];
#pragma unroll
        for (int j = 0; j < 8; ++j)
            pk[j] = bf16rne(p[2 * j]) | (bf16rne(p[2 * j + 1]) << 16);

        unsigned x0 = (unsigned)__shfl_xor((int)pk[0], 32, 64);
        unsigned x1 = (unsigned)__shfl_xor((int)pk[1], 32, 64);
        unsigned x2 = (unsigned)__shfl_xor((int)pk[2], 32, 64);
        unsigned x3 = (unsigned)__shfl_xor((int)pk[3], 32, 64);
        unsigned x4 = (unsigned)__shfl_xor((int)pk[4], 32, 64);
        unsigned x5 = (unsigned)__shfl_xor((int)pk[5], 32, 64);
        unsigned x6 = (unsigned)__shfl_xor((int)pk[6], 32, 64);
        unsigned x7 = (unsigned)__shfl_xor((int)pk[7], 32, 64);

        union { unsigned u[4]; short8 s; } pa0, pa1;
        pa0.u[0] = hi ? x2 : pk[0];
        pa0.u[1] = hi ? x3 : pk[1];
        pa0.u[2] = hi ? pk[2] : x0;
        pa0.u[3] = hi ? pk[3] : x1;
        pa1.u[0] = hi ? x6 : pk[4];
        pa1.u[1] = hi ? x7 : pk[5];
        pa1.u[2] = hi ? pk[6] : x4;
        pa1.u[3] = hi ? pk[7] : x5;

#pragma unroll
        for (int cc = 0; cc < 2; ++cc) {
            const short8 pb = cc ? pa1.s : pa0.s;
            union { int2 p[2]; short8 s; } va, vb;
            va.p[0] = *reinterpret_cast<const int2*>(&Vs[ql][cc * 16 + hi * 8]);
            va.p[1] = *reinterpret_cast<const int2*>(&Vs[ql][cc * 16 + hi * 8 + 4]);
            vb.p[0] = *reinterpret_cast<const int2*>(&Vs[ql + 32][cc * 16 + hi * 8]);
            vb.p[1] = *reinterpret_cast<const int2*>(&Vs[ql + 32][cc * 16 + hi * 8 + 4]);
            accA = __builtin_amdgcn_mfma_f32_32x32x16_bf16(va.s, pb, accA, 0, 0, 0);
            accB = __builtin_amdgcn_mfma_f32_32x32x16_bf16(vb.s, pb, accB, 0, 0, 0);
        }
    }

    const float inv = (lrow > 0.f) ? 1.f / lrow : 0.f;
    ushort* crow_ = ctx + ((size_t)b * S_ + q0w + ql) * D_ + h * DK_;
#pragma unroll
    for (int g = 0; g < 4; ++g) {
        ushort4 oA, oB;
        oA.x = (ushort)bf16rne(accA[4 * g + 0] * inv);
        oA.y = (ushort)bf16rne(accA[4 * g + 1] * inv);
        oA.z = (ushort)bf16rne(accA[4 * g + 2] * inv);
        oA.w = (ushort)bf16rne(accA[4 * g + 3] * inv);
        oB.x = (ushort)bf16rne(accB[4 * g + 0] * inv);
        oB.y = (ushort)bf16rne(accB[4 * g + 1] * inv);
        oB.z = (ushort)bf16rne(accB[4 * g + 2] * inv);
        oB.w = (ushort)bf16rne(accB[4 * g + 3] * inv);
        *reinterpret_cast<ushort4*>(&crow_[g * 8 + hi * 4])      = oA;
        *reinterpret_cast<ushort4*>(&crow_[g * 8 + hi * 4 + 32]) = oB;
    }
}

// ---------------------------------------------------------------------------
// LayerNorm over last dim (1024).
// ---------------------------------------------------------------------------
__global__ __launch_bounds__(256) void layernorm_k(
    const float* __restrict__ x, const float* __restrict__ gamma,
    const float* __restrict__ beta, float* __restrict__ out)
{
    const int row = blockIdx.x;
    const int t   = threadIdx.x;
    const float4 v = *reinterpret_cast<const float4*>(&x[(size_t)row * D_ + (t << 2)]);
    float sum = v.x + v.y + v.z + v.w;
    float sq  = v.x * v.x + v.y * v.y + v.z * v.z + v.w * v.w;
#pragma unroll
    for (int w = 1; w < 64; w <<= 1) {
        sum += __shfl_xor(sum, w, 64);
        sq  += __shfl_xor(sq,  w, 64);
    }
    __shared__ float red[8];
    const int wid = t >> 6;
    if ((t & 63) == 0) { red[wid] = sum; red[wid + 4] = sq; }
    __syncthreads();
    sum = red[0] + red[1] + red[2] + red[3];
    sq  = red[4] + red[5] + red[6] + red[7];
    const float mu  = sum * (1.f / 1024.f);
    const float var = sq * (1.f / 1024.f) - mu * mu;
    const float rs  = rsqrtf(var + 1e-5f);
    const float4 gm = *reinterpret_cast<const float4*>(&gamma[t << 2]);
    const float4 bt = *reinterpret_cast<const float4*>(&beta[t << 2]);
    float4 o;
    o.x = (v.x - mu) * rs * gm.x + bt.x;
    o.y = (v.y - mu) * rs * gm.y + bt.y;
    o.z = (v.z - mu) * rs * gm.z + bt.z;
    o.w = (v.w - mu) * rs * gm.w + bt.w;
    *reinterpret_cast<float4*>(&out[(size_t)row * D_ + (t << 2)]) = o;
}

// ---------------------------------------------------------------------------
extern "C" void kernel_launch(void* const* d_in, const int* in_sizes, int n_in,
                              void* d_out, int out_size, void* d_ws, size_t ws_size,
                              hipStream_t stream)
{
    const float* query  = (const float*)d_in[0];
    const float* key    = (const float*)d_in[1];
    const float* values = (const float*)d_in[2];
    const float* SW     = (const float*)d_in[4];
    const float* Wq     = (const float*)d_in[5];
    const float* bq     = (const float*)d_in[6];
    const float* Wv     = (const float*)d_in[7];
    const float* bv     = (const float*)d_in[8];
    const float* Wo     = (const float*)d_in[9];
    const float* bo     = (const float*)d_in[10];
    const float* gamma  = (const float*)d_in[11];
    const float* beta   = (const float*)d_in[12];

    char* ws = (char*)d_ws;
    const size_t MB = 1024 * 1024;
    ushort* qbf = (ushort*)(ws);              //  8 MB bf16 [4096][1024]
    ushort* kbf = (ushort*)(ws +  8 * MB);
    ushort* vbf = (ushort*)(ws + 16 * MB);
    ushort* Wqt = (ushort*)(ws + 24 * MB);    //  2 MB bf16 [n][k]
    ushort* Wvt = (ushort*)(ws + 26 * MB);
    ushort* Wot = (ushort*)(ws + 28 * MB);
    ushort* Qh  = (ushort*)(ws + 30 * MB);    //  8 MB bf16 [bh][S][DK]
    ushort* Kh  = (ushort*)(ws + 38 * MB);
    ushort* Vt  = (ushort*)(ws + 46 * MB);    //  8 MB bf16 [bh][DK][S]
    ushort* ctxb = qbf;                        // reuse after projections
    float*  xbf  = (float*)(ws + 8 * MB);      // 16 MB fp32, overlays kbf+vbf

    const dim3 blk(256);

    cvt_bf16<<<dim3(2048), blk, 0, stream>>>(query,  qbf);
    cvt_bf16<<<dim3(2048), blk, 0, stream>>>(key,    kbf);
    cvt_bf16<<<dim3(2048), blk, 0, stream>>>(values, vbf);
    transpose_cvt<<<dim3(32, 32), blk, 0, stream>>>(Wq, Wqt);
    transpose_cvt<<<dim3(32, 32), blk, 0, stream>>>(Wv, Wvt);
    transpose_cvt<<<dim3(32, 32), blk, 0, stream>>>(Wo, Wot);

    gemm_mfma<1><<<dim3(256), blk, 0, stream>>>(qbf, Wqt, bq, nullptr, Qh);
    gemm_mfma<1><<<dim3(256), blk, 0, stream>>>(kbf, Wqt, bq, nullptr, Kh);   // kq_same
    gemm_mfma<2><<<dim3(256), blk, 0, stream>>>(vbf, Wvt, bv, nullptr, Vt);

    attn_mfma<<<dim3(512), blk, 0, stream>>>(Qh, Kh, Vt, SW, ctxb);

    gemm_mfma<0><<<dim3(256), blk, 0, stream>>>(ctxb, Wot, bo, query, xbf);

    layernorm_k<<<dim3(4096), blk, 0, stream>>>(xbf, gamma, beta, (float*)d_out);
}

// Round 4
// 139.646 us; speedup vs baseline: 9.0836x; 1.3941x over previous
//
#include <hip/hip_runtime.h>

#define B_ 4
#define S_ 1024
#define D_ 1024
#define H_ 16
#define DK_ 64

typedef __attribute__((ext_vector_type(8))) short short8;
typedef __attribute__((ext_vector_type(4))) float f32x4;
typedef __attribute__((ext_vector_type(16))) float f32x16;

static __device__ __forceinline__ unsigned bf16rne(float x) {
    unsigned b = __float_as_uint(x);
    return (b + 0x7FFFu + ((b >> 16) & 1u)) >> 16;
}

// ---------------------------------------------------------------------------
// fp32 -> bf16 convert for q,k,v in one launch. 12M elements, 8/thread.
// q,k,v outputs are contiguous (qbf|kbf|vbf).
// ---------------------------------------------------------------------------
__global__ __launch_bounds__(256) void cvt3_bf16(
    const float* __restrict__ q, const float* __restrict__ k,
    const float* __restrict__ v, ushort* __restrict__ out)
{
    const size_t i = ((size_t)blockIdx.x * 256 + threadIdx.x) * 8;
    const size_t FM = (size_t)4 * 1024 * 1024;   // elems per tensor
    const float* in = (i < FM) ? q : (i < 2 * FM) ? k : v;
    const size_t off = i & (FM - 1);
    const float4 a = *reinterpret_cast<const float4*>(in + off);
    const float4 b = *reinterpret_cast<const float4*>(in + off + 4);
    union { ushort u[8]; int4 vv; } p;
    p.u[0] = (ushort)bf16rne(a.x); p.u[1] = (ushort)bf16rne(a.y);
    p.u[2] = (ushort)bf16rne(a.z); p.u[3] = (ushort)bf16rne(a.w);
    p.u[4] = (ushort)bf16rne(b.x); p.u[5] = (ushort)bf16rne(b.y);
    p.u[6] = (ushort)bf16rne(b.z); p.u[7] = (ushort)bf16rne(b.w);
    *reinterpret_cast<int4*>(out + i) = p.vv;
}

// ---------------------------------------------------------------------------
// W [1024][1024] fp32 -> Wt [n][k] bf16 (transpose + convert). z selects W.
// ---------------------------------------------------------------------------
__global__ __launch_bounds__(256) void transpose_cvt3(
    const float* __restrict__ W0, const float* __restrict__ W1,
    const float* __restrict__ W2, ushort* __restrict__ T0,
    ushort* __restrict__ T1, ushort* __restrict__ T2)
{
    __shared__ float ts[32][33];
    const float* W = (blockIdx.z == 0) ? W0 : (blockIdx.z == 1) ? W1 : W2;
    ushort*     Wt = (blockIdx.z == 0) ? T0 : (blockIdx.z == 1) ? T1 : T2;
    const int t  = threadIdx.x;
    const int k0 = blockIdx.y * 32, n0 = blockIdx.x * 32;
    const int r  = t >> 3, c4 = (t & 7) * 4;
    const float4 v = *reinterpret_cast<const float4*>(&W[(size_t)(k0 + r) * 1024 + n0 + c4]);
    ts[r][c4] = v.x; ts[r][c4 + 1] = v.y; ts[r][c4 + 2] = v.z; ts[r][c4 + 3] = v.w;
    __syncthreads();
    ushort4 o;
    o.x = (ushort)bf16rne(ts[c4    ][r]);
    o.y = (ushort)bf16rne(ts[c4 + 1][r]);
    o.z = (ushort)bf16rne(ts[c4 + 2][r]);
    o.w = (ushort)bf16rne(ts[c4 + 3][r]);
    *reinterpret_cast<ushort4*>(&Wt[(size_t)(n0 + r) * 1024 + k0 + c4]) = o;
}

// ---------------------------------------------------------------------------
// bf16 MFMA GEMM: C[M,1024] = X[M,1024] @ Wt^T (+bias, +resid).
// BM=64, BN=128, BK=64; 4 waves (2x2), each 32x64 = 2x4 frags of 16x16x32.
// Single-buffered LDS (24KB, m97 2-barrier loop), global_load_lds(16B),
// XOR-swizzled reads, chunked XCD swizzle. Grid = (M/64)*8 blocks.
// MODE 0: fp32 + resid. MODE 1: merged QK, bf16 headed -> out0/out1 by half.
// MODE 2: bf16 [bh][DK][S].
// ---------------------------------------------------------------------------
template<int MODE>
__global__ __launch_bounds__(256) void gemm_mfma(
    const ushort* __restrict__ X, const ushort* __restrict__ Wt,
    const float* __restrict__ bias, const float* __restrict__ resid,
    void* __restrict__ out0, void* __restrict__ out1)
{
    __shared__ ushort As[64 * 64];
    __shared__ ushort Bs[128 * 64];

    const int t    = threadIdx.x;
    const int lane = t & 63;
    const int w    = t >> 6;

    // chunked XCD swizzle (grid % 8 == 0)
    const int cpx     = gridDim.x >> 3;
    const int logical = (blockIdx.x & 7) * cpx + (blockIdx.x >> 3);
    const int bm = logical >> 3;
    const int bn = logical & 7;

    const int srow   = lane >> 3;
    const int schunk = (lane & 7) ^ srow;
    const ushort* ag[2];
    const ushort* bg[4];
#pragma unroll
    for (int j = 0; j < 2; ++j)
        ag[j] = X  + (size_t)(bm * 64 + (j * 4 + w) * 8 + srow) * 1024 + schunk * 8;
#pragma unroll
    for (int j = 0; j < 4; ++j)
        bg[j] = Wt + (size_t)(bn * 128 + (j * 4 + w) * 8 + srow) * 1024 + schunk * 8;

#define STAGE(k0)                                                                \
    do {                                                                         \
        _Pragma("unroll")                                                        \
        for (int j = 0; j < 2; ++j)                                              \
            __builtin_amdgcn_global_load_lds(                                    \
                (__attribute__((address_space(1))) const void*)(ag[j] + (k0)),   \
                (__attribute__((address_space(3))) void*)&As[(j * 4 + w) * 512], \
                16, 0, 0);                                                       \
        _Pragma("unroll")                                                        \
        for (int j = 0; j < 4; ++j)                                              \
            __builtin_amdgcn_global_load_lds(                                    \
                (__attribute__((address_space(1))) const void*)(bg[j] + (k0)),   \
                (__attribute__((address_space(3))) void*)&Bs[(j * 4 + w) * 512], \
                16, 0, 0);                                                       \
    } while (0)

    const int fr = lane & 15;
    const int fk = lane >> 4;
    const int wm = w >> 1, wn = w & 1;

    f32x4 acc[2][4];
#pragma unroll
    for (int m = 0; m < 2; ++m)
#pragma unroll
        for (int n = 0; n < 4; ++n) acc[m][n] = (f32x4){0.f, 0.f, 0.f, 0.f};

#pragma unroll 1
    for (int kt = 0; kt < 16; ++kt) {
        STAGE(kt * 64);
        __syncthreads();
#pragma unroll
        for (int ks = 0; ks < 2; ++ks) {
            short8 af[2], bf[4];
#pragma unroll
            for (int m = 0; m < 2; ++m) {
                const int row = wm * 32 + m * 16 + fr;
                af[m] = *reinterpret_cast<const short8*>(
                    &As[row * 64 + (((ks * 4 + fk) ^ (row & 7)) * 8)]);
            }
#pragma unroll
            for (int n = 0; n < 4; ++n) {
                const int row = wn * 64 + n * 16 + fr;
                bf[n] = *reinterpret_cast<const short8*>(
                    &Bs[row * 64 + (((ks * 4 + fk) ^ (row & 7)) * 8)]);
            }
#pragma unroll
            for (int m = 0; m < 2; ++m)
#pragma unroll
                for (int n = 0; n < 4; ++n)
                    acc[m][n] = __builtin_amdgcn_mfma_f32_16x16x32_bf16(
                        af[m], bf[n], acc[m][n], 0, 0, 0);
        }
        __syncthreads();
    }
#undef STAGE

#pragma unroll
    for (int m = 0; m < 2; ++m) {
        const int row0 = bm * 64 + wm * 32 + m * 16 + fk * 4;
#pragma unroll
        for (int n = 0; n < 4; ++n) {
            const int col = bn * 128 + wn * 64 + n * 16 + fr;
            const float bc = bias[col];
            if (MODE == 0) {
                float* o = (float*)out0;
#pragma unroll
                for (int j = 0; j < 4; ++j) {
                    const int row = row0 + j;
                    o[(size_t)row * 1024 + col] =
                        acc[m][n][j] + bc + resid[(size_t)row * 1024 + col];
                }
            } else if (MODE == 1) {
                ushort* o = (row0 < 4096) ? (ushort*)out0 : (ushort*)out1;
                const int r0 = row0 & 4095;
                const int b_ = r0 >> 10, s0 = r0 & 1023;
                const int h  = col >> 6,  dk = col & 63;
#pragma unroll
                for (int j = 0; j < 4; ++j)
                    o[(((size_t)b_ * H_ + h) * S_ + s0 + j) * DK_ + dk] =
                        (ushort)bf16rne(acc[m][n][j] + bc);
            } else {
                ushort* o = (ushort*)out0;
                const int b_ = row0 >> 10, s0 = row0 & 1023;
                const int h  = col >> 6,   dk = col & 63;
                ushort4 pk;
                pk.x = (ushort)bf16rne(acc[m][n][0] + bc);
                pk.y = (ushort)bf16rne(acc[m][n][1] + bc);
                pk.z = (ushort)bf16rne(acc[m][n][2] + bc);
                pk.w = (ushort)bf16rne(acc[m][n][3] + bc);
                *reinterpret_cast<ushort4*>(
                    &o[(((size_t)b_ * H_ + h) * DK_ + dk) * S_ + s0]) = pk;
            }
        }
    }
}

// ---------------------------------------------------------------------------
// MFMA bf16 flash attention v2. KVBLK=64, double-buffered global_load_lds
// staging with counted vmcnt, interleaved q-rows (qrow = qb*128 + ql*4 + w)
// so all waves work on every tile. Swapped-operand form throughout.
// ---------------------------------------------------------------------------
__global__ __launch_bounds__(256) void attn_mfma(
    const ushort* __restrict__ Qh, const ushort* __restrict__ Kh,
    const ushort* __restrict__ Vt, const float* __restrict__ SW,
    ushort* __restrict__ ctx)
{
    __shared__ ushort Ks[2][64 * 64];
    __shared__ ushort Vs[2][64 * 64];

    const int t    = threadIdx.x;
    const int lane = t & 63;
    const int w    = t >> 6;
    const int bid  = blockIdx.x;
    const int bh   = bid & 63;
    const int b    = bh >> 4;
    const int h    = bh & 15;
    int qb = bid >> 6;
    qb = (qb < 4) ? qb : 11 - qb;            // pair heavy/light blocks

    const int ql = lane & 31;
    const int hi = lane >> 5;
    const int qrow  = qb * 128 + ql * 4 + w; // interleaved: balanced causal work
    const int maxt  = 2 * qb + 2;            // 64-key tiles

    const ushort* Kg  = Kh + (size_t)bh * S_ * DK_;
    const ushort* Vg  = Vt + (size_t)bh * DK_ * S_;
    const float*  swp = SW + ((size_t)h * S_ + qrow) * S_;

    // staging source pointers (inverse-swizzled chunk)
    const int srow   = lane >> 3;
    const int schunk = (lane & 7) ^ srow;
    const ushort* kg[2];
    const ushort* vg[2];
#pragma unroll
    for (int j = 0; j < 2; ++j) {
        kg[j] = Kg + (size_t)((j * 4 + w) * 8 + srow) * DK_ + schunk * 8;
        vg[j] = Vg + (size_t)((j * 4 + w) * 8 + srow) * S_  + schunk * 8;
    }

#define ASTAGE(buf, k0)                                                          \
    do {                                                                         \
        _Pragma("unroll")                                                        \
        for (int j = 0; j < 2; ++j) {                                            \
            __builtin_amdgcn_global_load_lds(                                    \
                (__attribute__((address_space(1))) const void*)(kg[j] + (size_t)(k0) * DK_), \
                (__attribute__((address_space(3))) void*)&Ks[buf][(j * 4 + w) * 512], \
                16, 0, 0);                                                       \
            __builtin_amdgcn_global_load_lds(                                    \
                (__attribute__((address_space(1))) const void*)(vg[j] + (k0)),   \
                (__attribute__((address_space(3))) void*)&Vs[buf][(j * 4 + w) * 512], \
                16, 0, 0);                                                       \
        }                                                                        \
    } while (0)

    // Q fragments from global: lane's q-row, dk = c*16 + hi*8 + i
    short8 qf[4];
    {
        const ushort* Qg = Qh + ((size_t)bh * S_ + qrow) * DK_;
#pragma unroll
        for (int c = 0; c < 4; ++c) {
            union { int4 i; short8 s; } u;
            u.i = *reinterpret_cast<const int4*>(&Qg[c * 16 + hi * 8]);
            qf[c] = u.s;
        }
    }

    f32x16 accA, accB;
#pragma unroll
    for (int r = 0; r < 16; ++r) { accA[r] = 0.f; accB[r] = 0.f; }
    float mrow = -1e30f, lrow = 0.f;

    ASTAGE(0, 0);

#pragma unroll 1
    for (int kt = 0; kt < maxt; ++kt) {
        const int cur = kt & 1;
        const int k0  = kt * 64;
        if (kt + 1 < maxt) {
            ASTAGE(cur ^ 1, (kt + 1) * 64);
            asm volatile("s_waitcnt vmcnt(4)" ::: "memory");
        } else {
            asm volatile("s_waitcnt vmcnt(0)" ::: "memory");
        }
        __builtin_amdgcn_s_barrier();
        __builtin_amdgcn_sched_barrier(0);

        // ---- QK^T (swapped): group g covers keys k0+g*32 .. +31 ----
        f32x16 sc[2];
#pragma unroll
        for (int g = 0; g < 2; ++g) {
#pragma unroll
            for (int r = 0; r < 16; ++r) sc[g][r] = 0.f;
            const int row = g * 32 + ql;
#pragma unroll
            for (int c = 0; c < 4; ++c) {
                union { int2 p[2]; short8 s; } u;
                const int ch = ((c * 2 + hi) ^ (row & 7)) * 8;
                u.p[0] = *reinterpret_cast<const int2*>(&Ks[cur][row * 64 + ch]);
                u.p[1] = *reinterpret_cast<const int2*>(&Ks[cur][row * 64 + ch + 4]);
                sc[g] = __builtin_amdgcn_mfma_f32_32x32x16_bf16(u.s, qf[c], sc[g], 0, 0, 0);
            }
        }

        // ---- state_weight gathers (lane's own q-row) ----
        float swv[2][16];
#pragma unroll
        for (int g = 0; g < 2; ++g)
#pragma unroll
            for (int j = 0; j < 4; ++j) {
                const float4 v = *reinterpret_cast<const float4*>(
                    &swp[k0 + g * 32 + hi * 4 + j * 8]);
                swv[g][j * 4 + 0] = v.x; swv[g][j * 4 + 1] = v.y;
                swv[g][j * 4 + 2] = v.z; swv[g][j * 4 + 3] = v.w;
            }

        // ---- masked scores + online softmax (lane-local + one shfl) ----
        float p[2][16];
        float tmax = -1e30f;
#pragma unroll
        for (int g = 0; g < 2; ++g)
#pragma unroll
            for (int r = 0; r < 16; ++r) {
                const int key = k0 + g * 32 + (r & 3) + ((r >> 2) << 3) + (hi << 2);
                const float s = (key < qrow) ? sc[g][r] * 0.125f + swv[g][r] : -1e30f;
                p[g][r] = s;
                tmax = fmaxf(tmax, s);
            }
        tmax = fmaxf(tmax, __shfl_xor(tmax, 32, 64));
        const float mnew = fmaxf(mrow, tmax);
        const float corr = __expf(mrow - mnew);
        float psum = 0.f;
#pragma unroll
        for (int g = 0; g < 2; ++g)
#pragma unroll
            for (int r = 0; r < 16; ++r) {
                const float e = (p[g][r] > -1e29f) ? __expf(p[g][r] - mnew) : 0.f;
                p[g][r] = e;
                psum += e;
            }
        psum += __shfl_xor(psum, 32, 64);
        lrow = lrow * corr + psum;
        mrow = mnew;
#pragma unroll
        for (int r = 0; r < 16; ++r) { accA[r] *= corr; accB[r] *= corr; }

        // ---- P -> bf16 B-fragments (pk pairs + cross-half exchange) ----
        short8 paf[4];
#pragma unroll
        for (int g = 0; g < 2; ++g) {
            unsigned pk[8];
#pragma unroll
            for (int j = 0; j < 8; ++j)
                pk[j] = bf16rne(p[g][2 * j]) | (bf16rne(p[g][2 * j + 1]) << 16);
            unsigned x0 = (unsigned)__shfl_xor((int)pk[0], 32, 64);
            unsigned x1 = (unsigned)__shfl_xor((int)pk[1], 32, 64);
            unsigned x2 = (unsigned)__shfl_xor((int)pk[2], 32, 64);
            unsigned x3 = (unsigned)__shfl_xor((int)pk[3], 32, 64);
            unsigned x4 = (unsigned)__shfl_xor((int)pk[4], 32, 64);
            unsigned x5 = (unsigned)__shfl_xor((int)pk[5], 32, 64);
            unsigned x6 = (unsigned)__shfl_xor((int)pk[6], 32, 64);
            unsigned x7 = (unsigned)__shfl_xor((int)pk[7], 32, 64);
            union { unsigned u[4]; short8 s; } a0, a1;
            a0.u[0] = hi ? x2 : pk[0];
            a0.u[1] = hi ? x3 : pk[1];
            a0.u[2] = hi ? pk[2] : x0;
            a0.u[3] = hi ? pk[3] : x1;
            a1.u[0] = hi ? x6 : pk[4];
            a1.u[1] = hi ? x7 : pk[5];
            a1.u[2] = hi ? pk[6] : x4;
            a1.u[3] = hi ? pk[7] : x5;
            paf[g * 2 + 0] = a0.s;
            paf[g * 2 + 1] = a1.s;
        }

        // ---- PV (swapped): acc[dk][q] += V^T · P^T over 64 keys ----
#pragma unroll
        for (int cc = 0; cc < 4; ++cc) {
            const int rowA = ql, rowB = ql + 32;
            const int chA = ((cc * 2 + hi) ^ (rowA & 7)) * 8;
            union { int2 pp[2]; short8 s; } va, vb;
            va.pp[0] = *reinterpret_cast<const int2*>(&Vs[cur][rowA * 64 + chA]);
            va.pp[1] = *reinterpret_cast<const int2*>(&Vs[cur][rowA * 64 + chA + 4]);
            vb.pp[0] = *reinterpret_cast<const int2*>(&Vs[cur][rowB * 64 + chA]);
            vb.pp[1] = *reinterpret_cast<const int2*>(&Vs[cur][rowB * 64 + chA + 4]);
            accA = __builtin_amdgcn_mfma_f32_32x32x16_bf16(va.s, paf[cc], accA, 0, 0, 0);
            accB = __builtin_amdgcn_mfma_f32_32x32x16_bf16(vb.s, paf[cc], accB, 0, 0, 0);
        }

        __builtin_amdgcn_sched_barrier(0);
        __builtin_amdgcn_s_barrier();       // readers done before next restage
        __builtin_amdgcn_sched_barrier(0);
    }
#undef ASTAGE

    // ---- epilogue ----
    const float inv = (lrow > 0.f) ? 1.f / lrow : 0.f;   // row 0 fully masked -> 0
    ushort* crow_ = ctx + ((size_t)b * S_ + qrow) * D_ + h * DK_;
#pragma unroll
    for (int g = 0; g < 4; ++g) {
        ushort4 oA, oB;
        oA.x = (ushort)bf16rne(accA[4 * g + 0] * inv);
        oA.y = (ushort)bf16rne(accA[4 * g + 1] * inv);
        oA.z = (ushort)bf16rne(accA[4 * g + 2] * inv);
        oA.w = (ushort)bf16rne(accA[4 * g + 3] * inv);
        oB.x = (ushort)bf16rne(accB[4 * g + 0] * inv);
        oB.y = (ushort)bf16rne(accB[4 * g + 1] * inv);
        oB.z = (ushort)bf16rne(accB[4 * g + 2] * inv);
        oB.w = (ushort)bf16rne(accB[4 * g + 3] * inv);
        *reinterpret_cast<ushort4*>(&crow_[g * 8 + hi * 4])      = oA;
        *reinterpret_cast<ushort4*>(&crow_[g * 8 + hi * 4 + 32]) = oB;
    }
}

// ---------------------------------------------------------------------------
// LayerNorm over last dim (1024).
// ---------------------------------------------------------------------------
__global__ __launch_bounds__(256) void layernorm_k(
    const float* __restrict__ x, const float* __restrict__ gamma,
    const float* __restrict__ beta, float* __restrict__ out)
{
    const int row = blockIdx.x;
    const int t   = threadIdx.x;
    const float4 v = *reinterpret_cast<const float4*>(&x[(size_t)row * D_ + (t << 2)]);
    float sum = v.x + v.y + v.z + v.w;
    float sq  = v.x * v.x + v.y * v.y + v.z * v.z + v.w * v.w;
#pragma unroll
    for (int w = 1; w < 64; w <<= 1) {
        sum += __shfl_xor(sum, w, 64);
        sq  += __shfl_xor(sq,  w, 64);
    }
    __shared__ float red[8];
    const int wid = t >> 6;
    if ((t & 63) == 0) { red[wid] = sum; red[wid + 4] = sq; }
    __syncthreads();
    sum = red[0] + red[1] + red[2] + red[3];
    sq  = red[4] + red[5] + red[6] + red[7];
    const float mu  = sum * (1.f / 1024.f);
    const float var = sq * (1.f / 1024.f) - mu * mu;
    const float rs  = rsqrtf(var + 1e-5f);
    const float4 gm = *reinterpret_cast<const float4*>(&gamma[t << 2]);
    const float4 bt = *reinterpret_cast<const float4*>(&beta[t << 2]);
    float4 o;
    o.x = (v.x - mu) * rs * gm.x + bt.x;
    o.y = (v.y - mu) * rs * gm.y + bt.y;
    o.z = (v.z - mu) * rs * gm.z + bt.z;
    o.w = (v.w - mu) * rs * gm.w + bt.w;
    *reinterpret_cast<float4*>(&out[(size_t)row * D_ + (t << 2)]) = o;
}

// ---------------------------------------------------------------------------
extern "C" void kernel_launch(void* const* d_in, const int* in_sizes, int n_in,
                              void* d_out, int out_size, void* d_ws, size_t ws_size,
                              hipStream_t stream)
{
    const float* query  = (const float*)d_in[0];
    const float* key    = (const float*)d_in[1];
    const float* values = (const float*)d_in[2];
    const float* SW     = (const float*)d_in[4];
    const float* Wq     = (const float*)d_in[5];
    const float* bq     = (const float*)d_in[6];
    const float* Wv     = (const float*)d_in[7];
    const float* bv     = (const float*)d_in[8];
    const float* Wo     = (const float*)d_in[9];
    const float* bo     = (const float*)d_in[10];
    const float* gamma  = (const float*)d_in[11];
    const float* beta   = (const float*)d_in[12];

    char* ws = (char*)d_ws;
    const size_t MB = 1024 * 1024;
    ushort* qbf = (ushort*)(ws);              //  8 MB bf16 [4096][1024]  (qbf|kbf contiguous)
    ushort* kbf = (ushort*)(ws +  8 * MB);
    ushort* vbf = (ushort*)(ws + 16 * MB);
    ushort* Wqt = (ushort*)(ws + 24 * MB);
    ushort* Wvt = (ushort*)(ws + 26 * MB);
    ushort* Wot = (ushort*)(ws + 28 * MB);
    ushort* Qh  = (ushort*)(ws + 30 * MB);    //  8 MB bf16 [bh][S][DK]
    ushort* Kh  = (ushort*)(ws + 38 * MB);
    ushort* Vt  = (ushort*)(ws + 46 * MB);    //  8 MB bf16 [bh][DK][S]
    ushort* ctxb = qbf;                        // reuse after projections
    float*  xbf  = (float*)(ws + 8 * MB);      // 16 MB fp32, overlays kbf+vbf

    const dim3 blk(256);

    cvt3_bf16<<<dim3(6144), blk, 0, stream>>>(query, key, values, qbf);
    transpose_cvt3<<<dim3(32, 32, 3), blk, 0, stream>>>(Wq, Wv, Wo, Wqt, Wvt, Wot);

    // merged Q|K projection (shared Wq/bq), M = 8192
    gemm_mfma<1><<<dim3(1024), blk, 0, stream>>>(qbf, Wqt, bq, nullptr, Qh, Kh);
    gemm_mfma<2><<<dim3(512),  blk, 0, stream>>>(vbf, Wvt, bv, nullptr, Vt, nullptr);

    attn_mfma<<<dim3(512), blk, 0, stream>>>(Qh, Kh, Vt, SW, ctxb);

    gemm_mfma<0><<<dim3(512), blk, 0, stream>>>(ctxb, Wot, bo, query, xbf, nullptr);

    layernorm_k<<<dim3(4096), blk, 0, stream>>>(xbf, gamma, beta, (float*)d_out);
}